// Round 1
// baseline (11.150 us; speedup 1.0000x reference)
//
#include <hip/hip_runtime.h>
#include <math.h>

// N rows of HH=55 scalars; q:(8,2048,110) fp32 -> x = reshape(N,55), N = 8*2048*2
#define N_ROWS 32768
#define HH 55

// One wave (64 lanes) per row; 4 waves (4 rows) per 256-thread block.
__global__ __launch_bounds__(256) void self_attn_img_kernel(
    const float* __restrict__ q,
    const float* __restrict__ Wq, const float* __restrict__ bq,
    const float* __restrict__ Wk, const float* __restrict__ bk,
    const float* __restrict__ Wv, const float* __restrict__ bv,
    const float* __restrict__ Wo, const float* __restrict__ bo,
    const float* __restrict__ gamma,
    float* __restrict__ out)
{
    const float g = gamma[0];

    if (g == 0.0f) {
        // y = gamma*attn_out + residual == residual == q (attn_out finite).
        // Pure vectorized copy; total elements divisible by 4.
        const int total4 = (N_ROWS * HH) / 4;           // 450,560 float4
        const float4* __restrict__ q4 = (const float4*)q;
        float4* __restrict__ o4 = (float4*)out;
        for (int i = blockIdx.x * blockDim.x + threadIdx.x; i < total4;
             i += gridDim.x * blockDim.x)
            o4[i] = q4[i];
        return;
    }

    // ---- Full path (exact algebraic reduction of the reference) ----
    // attn[i,j] = A x_i x_j + B x_i + C x_j + D ; softmax_j -> p_ij = softmax_j(s_i x_j),
    // s_i = A x_i + C. out_row_i = g*(E*m_i + F) + x_i, m_i = sum_j p_ij x_j,
    // A=Wq.Wk, C=bq.Wk, E=Wv.Wo, F=bv.Wo+bo.
    const int lane = threadIdx.x & 63;
    const int w    = threadIdx.x >> 6;                  // wave within block (0..3)
    const int row  = (blockIdx.x * blockDim.x + threadIdx.x) >> 6;
    const bool act = lane < HH;

    // Per-wave redundant scalar computation (55-elem dot products, L1-cached).
    float pA = 0.f, pC = 0.f, pE = 0.f, pF = 0.f;
    if (act) {
        const float wq = Wq[lane], bqv = bq[lane];
        const float wk = Wk[lane], bkv = bk[lane];
        const float wv = Wv[lane], bvv = bv[lane];
        const float wo = Wo[lane];
        (void)bkv; // B unused (cancels in softmax)
        pA = wq * wk; pC = bqv * wk; pE = wv * wo; pF = bvv * wo;
    }
    #pragma unroll
    for (int off = 32; off; off >>= 1) {
        pA += __shfl_xor(pA, off);
        pC += __shfl_xor(pC, off);
        pE += __shfl_xor(pE, off);
        pF += __shfl_xor(pF, off);
    }
    const float A = pA, C = pC, E = pE, F = pF + bo[0];

    if (row >= N_ROWS) return;

    const float xi = act ? q[row * HH + lane] : 0.0f;

    // Broadcast row through LDS.
    __shared__ float sx[4][HH];
    if (act) sx[w][lane] = xi;
    __syncthreads();

    // Row max/min across lanes (for exact softmax shift).
    float vmax = act ? xi : -__builtin_inff();
    float vmin = act ? xi :  __builtin_inff();
    #pragma unroll
    for (int off = 32; off; off >>= 1) {
        vmax = fmaxf(vmax, __shfl_xor(vmax, off));
        vmin = fminf(vmin, __shfl_xor(vmin, off));
    }

    const float s = fmaf(A, xi, C);
    const float shift = s * (s >= 0.0f ? vmax : vmin);

    float num = 0.f, den = 0.f;
    #pragma unroll
    for (int j = 0; j < HH; ++j) {
        const float xj = sx[w][j];                      // LDS broadcast read
        const float e  = __expf(fmaf(s, xj, -shift));
        den += e;
        num  = fmaf(e, xj, num);
    }
    const float m   = num / den;
    const float res = fmaf(g, fmaf(E, m, F), xi);
    if (act) out[row * HH + lane] = res;
}

extern "C" void kernel_launch(void* const* d_in, const int* in_sizes, int n_in,
                              void* d_out, int out_size, void* d_ws, size_t ws_size,
                              hipStream_t stream) {
    const float* q     = (const float*)d_in[0];
    const float* Wq    = (const float*)d_in[1];
    const float* bq    = (const float*)d_in[2];
    const float* Wk    = (const float*)d_in[3];
    const float* bk    = (const float*)d_in[4];
    const float* Wv    = (const float*)d_in[5];
    const float* bv    = (const float*)d_in[6];
    const float* Wo    = (const float*)d_in[7];
    const float* bo    = (const float*)d_in[8];
    const float* gamma = (const float*)d_in[9];
    float* out = (float*)d_out;

    const int blocks = N_ROWS / 4;  // one wave per row, 4 waves/block
    self_attn_img_kernel<<<blocks, 256, 0, stream>>>(
        q, Wq, bq, Wk, bk, Wv, bv, Wo, bo, gamma, out);
}

// Round 2
// 10.412 us; speedup vs baseline: 1.0709x; 1.0709x over previous
//
#include <hip/hip_runtime.h>
#include <math.h>

// N rows of HH=55 scalars; q:(8,2048,110) fp32 -> x = reshape(N,55), N = 8*2048*2
#define N_ROWS 32768
#define HH 55
#define NBLOCKS 2048   // 8 blocks/CU on 256 CUs — memory-bound sweet spot (G11)
#define NTHREADS 256

// Copy path: <=1 float4 per thread. Full path: one wave per row, 4 rows/wave
// grid-strided, x_j broadcast via __shfl (no LDS, no __syncthreads).
__global__ __launch_bounds__(NTHREADS) void self_attn_img_kernel(
    const float* __restrict__ q,
    const float* __restrict__ Wq, const float* __restrict__ bq,
    const float* __restrict__ Wk, const float* __restrict__ bk,
    const float* __restrict__ Wv, const float* __restrict__ bv,
    const float* __restrict__ Wo, const float* __restrict__ bo,
    const float* __restrict__ gamma,
    float* __restrict__ out)
{
    const float g = gamma[0];   // uniform s_load; L2-hit after first block

    if (g == 0.0f) {
        // y = gamma*attn_out + residual == q exactly (attn_out finite, fp32 math).
        const int total4 = (N_ROWS * HH) / 4;           // 450,560 float4
        const float4* __restrict__ q4 = (const float4*)q;
        float4* __restrict__ o4 = (float4*)out;
        for (int i = blockIdx.x * NTHREADS + threadIdx.x; i < total4;
             i += NBLOCKS * NTHREADS)                   // at most 1 iteration
            o4[i] = q4[i];
        return;
    }

    // ---- Full path: exact algebraic reduction of the reference ----
    // attn[i,j] = A x_i x_j + B x_i + C x_j + D; softmax_j -> p_ij = softmax_j(s_i x_j)
    // with s_i = A x_i + C (j-constant terms cancel). out_i = g*(E*m_i + F) + x_i,
    // m_i = sum_j p_ij x_j; A=Wq.Wk, C=bq.Wk, E=Wv.Wo, F=bv.Wo + bo.
    const int lane = threadIdx.x & 63;
    const bool act = lane < HH;

    float pA = 0.f, pC = 0.f, pE = 0.f, pF = 0.f;
    if (act) {
        const float wk = Wk[lane], wo = Wo[lane];
        pA = Wq[lane] * wk;
        pC = bq[lane] * wk;
        pE = Wv[lane] * wo;
        pF = bv[lane] * wo;
    }
    #pragma unroll
    for (int off = 32; off; off >>= 1) {
        pA += __shfl_xor(pA, off);
        pC += __shfl_xor(pC, off);
        pE += __shfl_xor(pE, off);
        pF += __shfl_xor(pF, off);
    }
    const float A = pA, C = pC, E = pE, F = pF + bo[0];

    const int wave0       = (blockIdx.x * NTHREADS + threadIdx.x) >> 6;
    const int total_waves = (NBLOCKS * NTHREADS) >> 6;  // 8192 -> 4 rows/wave

    for (int row = wave0; row < N_ROWS; row += total_waves) {
        const float xi = act ? q[row * HH + lane] : 0.0f;

        // Row max/min via butterfly (lanes >=55 hold +-inf identities).
        float vmax = act ? xi : -__builtin_inff();
        float vmin = act ? xi :  __builtin_inff();
        #pragma unroll
        for (int off = 32; off; off >>= 1) {
            vmax = fmaxf(vmax, __shfl_xor(vmax, off));
            vmin = fminf(vmin, __shfl_xor(vmin, off));
        }

        const float s     = fmaf(A, xi, C);
        const float shift = s * (s >= 0.0f ? vmax : vmin);  // exact row max of s*x_j

        float num = 0.f, den = 0.f;
        #pragma unroll
        for (int j = 0; j < HH; ++j) {
            const float xj = __shfl(xi, j);                 // broadcast lane j's x
            const float e  = __expf(fmaf(s, xj, -shift));
            den += e;
            num  = fmaf(e, xj, num);
        }
        const float res = fmaf(g, fmaf(E, num / den, F), xi);
        if (act) out[row * HH + lane] = res;
    }
}

extern "C" void kernel_launch(void* const* d_in, const int* in_sizes, int n_in,
                              void* d_out, int out_size, void* d_ws, size_t ws_size,
                              hipStream_t stream) {
    const float* q     = (const float*)d_in[0];
    const float* Wq    = (const float*)d_in[1];
    const float* bq    = (const float*)d_in[2];
    const float* Wk    = (const float*)d_in[3];
    const float* bk    = (const float*)d_in[4];
    const float* Wv    = (const float*)d_in[5];
    const float* bv    = (const float*)d_in[6];
    const float* Wo    = (const float*)d_in[7];
    const float* bo    = (const float*)d_in[8];
    const float* gamma = (const float*)d_in[9];
    float* out = (float*)d_out;

    self_attn_img_kernel<<<NBLOCKS, NTHREADS, 0, stream>>>(
        q, Wq, bq, Wk, bk, Wv, bv, Wo, bo, gamma, out);
}

// Round 3
// 10.321 us; speedup vs baseline: 1.0804x; 1.0089x over previous
//
#include <hip/hip_runtime.h>
#include <math.h>

// N rows of HH=55 scalars; q:(8,2048,110) fp32 -> x = reshape(N,55), N = 8*2048*2
#define N_ROWS 32768
#define HH 55
#define NTHREADS 512
#define TOTAL4 ((N_ROWS * HH) / 4)          // 450,560 float4
#define NBLOCKS ((TOTAL4 + NTHREADS - 1) / NTHREADS)   // 880 — exact cover, 1 float4/thread

__global__ __launch_bounds__(NTHREADS) void self_attn_img_kernel(
    const float* __restrict__ q,
    const float* __restrict__ Wq, const float* __restrict__ bq,
    const float* __restrict__ Wk, const float* __restrict__ bk,
    const float* __restrict__ Wv, const float* __restrict__ bv,
    const float* __restrict__ Wo, const float* __restrict__ bo,
    const float* __restrict__ gamma,
    float* __restrict__ out)
{
    // Issue the copy load BEFORE the gamma-dependent branch so the two global
    // loads are in flight concurrently (no control-dependence serialization).
    const int i = blockIdx.x * NTHREADS + threadIdx.x;   // exact: i < TOTAL4 always
    const float4 v = ((const float4*)q)[i];
    const float g = gamma[0];

    if (g == 0.0f) {
        // y = gamma*attn_out + residual == q exactly (attn_out finite, fp32 math).
        ((float4*)out)[i] = v;
        return;
    }

    // ---- Full path: exact algebraic reduction of the reference ----
    // attn[i,j] = A x_i x_j + B x_i + C x_j + D; softmax_j -> p_ij = softmax_j(s_i x_j)
    // with s_i = A x_i + C (j-constant terms cancel). out_i = g*(E*m_i + F) + x_i,
    // m_i = sum_j p_ij x_j; A=Wq.Wk, C=bq.Wk, E=Wv.Wo, F=bv.Wo + bo.
    const int lane = threadIdx.x & 63;
    const bool act = lane < HH;

    float pA = 0.f, pC = 0.f, pE = 0.f, pF = 0.f;
    if (act) {
        const float wk = Wk[lane], wo = Wo[lane];
        pA = Wq[lane] * wk;
        pC = bq[lane] * wk;
        pE = Wv[lane] * wo;
        pF = bv[lane] * wo;
    }
    #pragma unroll
    for (int off = 32; off; off >>= 1) {
        pA += __shfl_xor(pA, off);
        pC += __shfl_xor(pC, off);
        pE += __shfl_xor(pE, off);
        pF += __shfl_xor(pF, off);
    }
    const float A = pA, C = pC, E = pE, F = pF + bo[0];

    const int wave0       = (blockIdx.x * NTHREADS + threadIdx.x) >> 6;
    const int total_waves = (NBLOCKS * NTHREADS) >> 6;

    for (int row = wave0; row < N_ROWS; row += total_waves) {
        const float xi = act ? q[row * HH + lane] : 0.0f;

        // Row max/min via butterfly (lanes >=55 hold +-inf identities).
        float vmax = act ? xi : -__builtin_inff();
        float vmin = act ? xi :  __builtin_inff();
        #pragma unroll
        for (int off = 32; off; off >>= 1) {
            vmax = fmaxf(vmax, __shfl_xor(vmax, off));
            vmin = fminf(vmin, __shfl_xor(vmin, off));
        }

        const float s     = fmaf(A, xi, C);
        const float shift = s * (s >= 0.0f ? vmax : vmin);  // exact row-max of s*x_j

        float num = 0.f, den = 0.f;
        #pragma unroll
        for (int j = 0; j < HH; ++j) {
            const float xj = __shfl(xi, j);                 // broadcast lane j's x
            const float e  = __expf(fmaf(s, xj, -shift));
            den += e;
            num  = fmaf(e, xj, num);
        }
        const float res = fmaf(g, fmaf(E, num / den, F), xi);
        if (act) out[row * HH + lane] = res;
    }
}

extern "C" void kernel_launch(void* const* d_in, const int* in_sizes, int n_in,
                              void* d_out, int out_size, void* d_ws, size_t ws_size,
                              hipStream_t stream) {
    const float* q     = (const float*)d_in[0];
    const float* Wq    = (const float*)d_in[1];
    const float* bq    = (const float*)d_in[2];
    const float* Wk    = (const float*)d_in[3];
    const float* bk    = (const float*)d_in[4];
    const float* Wv    = (const float*)d_in[5];
    const float* bv    = (const float*)d_in[6];
    const float* Wo    = (const float*)d_in[7];
    const float* bo    = (const float*)d_in[8];
    const float* gamma = (const float*)d_in[9];
    float* out = (float*)d_out;

    self_attn_img_kernel<<<NBLOCKS, NTHREADS, 0, stream>>>(
        q, Wq, bq, Wk, bk, Wv, bv, Wo, bo, gamma, out);
}